// Round 3
// baseline (332.244 us; speedup 1.0000x reference)
//
#include <hip/hip_runtime.h>
#include <hip/hip_bf16.h>
#include <math.h>

// Problem constants
#define NH    16
#define HD    64
#define DM    1024
#define BSZ   8
#define CL    4096
#define SPLIT 8                 // cache chunks per (b,h); one block per chunk
#define CHUNK (CL / SPLIT)      // 512 positions per block (4 waves x 128)
#define PSTRIDE 68              // floats per partial: [0]=m [1]=l [2..3]=pad [4..67]=o

// Workspace layout (float-word offsets) — total ~465 KiB
#define WS_QH   0                                   // raw q heads   (8192)
#define WS_KH   8192                                // raw new-k     (8192)
#define WS_VH   16384                               // new-v         (8192)
#define WS_QROT 24576                               // roped q       (8192)
#define WS_KROT 32768                               // roped new-k   (8192)
#define WS_PART 40960                               // 128*8*68 = 69632 floats
#define WS_HEAD (40960 + 128 * SPLIT * PSTRIDE)     // head outputs  (8192)
#define WS_FLAG (WS_HEAD + 8192)                    // dtype flag (1 word)

#define LOG2_THETA 13.287712379549449               // log2(10000)
#define TWO_PI     6.283185307179586476925286766559
#define SM_SCALE_L2 (0.125f * 1.4426950408889634f)  // 1/sqrt(64) * log2(e)

__device__ __forceinline__ void bf2x(unsigned u, float& a, float& b) {
  union { unsigned i; float f; } lo, hi;
  lo.i = u << 16;
  hi.i = u & 0xffff0000u;
  a = lo.f; b = hi.f;
}

// ---- dtype-generic element access (DT=0: bf16, DT=1: f32) -----------------
template<int DT> __device__ __forceinline__ void load4(const void* p, long i4, float* o);
template<> __device__ __forceinline__ void load4<0>(const void* p, long i4, float* o) {
  uint2 w = ((const uint2*)p)[i4];
  bf2x(w.x, o[0], o[1]); bf2x(w.y, o[2], o[3]);
}
template<> __device__ __forceinline__ void load4<1>(const void* p, long i4, float* o) {
  float4 f = ((const float4*)p)[i4];
  o[0] = f.x; o[1] = f.y; o[2] = f.z; o[3] = f.w;
}

template<int DT> __device__ __forceinline__ void load8(const void* p, long i8, float* o);
template<> __device__ __forceinline__ void load8<0>(const void* p, long i8, float* o) {
  uint4 u = ((const uint4*)p)[i8];
  bf2x(u.x, o[0], o[1]); bf2x(u.y, o[2], o[3]);
  bf2x(u.z, o[4], o[5]); bf2x(u.w, o[6], o[7]);
}
template<> __device__ __forceinline__ void load8<1>(const void* p, long i8, float* o) {
  const float4* f = (const float4*)p + 2 * i8;
  float4 a = f[0], b = f[1];
  o[0] = a.x; o[1] = a.y; o[2] = a.z; o[3] = a.w;
  o[4] = b.x; o[5] = b.y; o[6] = b.z; o[7] = b.w;
}

template<int DT> __device__ __forceinline__ float ld1(const void* p, int i);
template<> __device__ __forceinline__ float ld1<0>(const void* p, int i) {
  return __bfloat162float(((const __hip_bfloat16*)p)[i]);
}
template<> __device__ __forceinline__ float ld1<1>(const void* p, int i) {
  return ((const float*)p)[i];
}

template<int DT> __device__ __forceinline__ void st1(void* p, int i, float v);
template<> __device__ __forceinline__ void st1<0>(void* p, int i, float v) {
  ((__hip_bfloat16*)p)[i] = __float2bfloat16(v);
}
template<> __device__ __forceinline__ void st1<1>(void* p, int i, float v) {
  ((float*)p)[i] = v;
}

// ---------------------------------------------------------------------------
// Kernel 0: dtype detection. Read q's first 4096 32-bit words as bf16 pairs;
// f32 data yields huge/NaN bf16 patterns from mantissa bits (~950 expected
// hits over 8192 views), bf16 data (N(0,1)) never exceeds ~10.
// flag: 0 = bf16, 1 = f32. grid = 1 x 256
// ---------------------------------------------------------------------------
__global__ __launch_bounds__(256) void detect_dtype(const unsigned* __restrict__ qw,
                                                    float* __restrict__ ws)
{
  __shared__ int s;
  if (threadIdx.x == 0) s = 0;
  __syncthreads();
  int bad = 0;
  for (int i = threadIdx.x; i < 4096; i += 256) {
    float a, b;
    bf2x(qw[i], a, b);
    if (!(fabsf(a) < 1e10f) || !(fabsf(b) < 1e10f)) bad = 1;  // catches NaN too
  }
  if (bad) atomicOr(&s, 1);
  __syncthreads();
  if (threadIdx.x == 0) ((unsigned*)ws)[WS_FLAG] = (unsigned)s;
}

__device__ __forceinline__ bool active(const float* ws, int DT) {
  return ((const unsigned*)ws)[WS_FLAG] == (unsigned)DT;
}

// ---------------------------------------------------------------------------
// Kernel A: fused QKV GEMV. One wave per (proj, out-col j); computes all 8
// batches so each weight row is read exactly once. grid = 768 x 256
// ---------------------------------------------------------------------------
template<int DT>
__global__ __launch_bounds__(256) void qkv_gemv(
    const void* __restrict__ x,
    const void* __restrict__ wq, const void* __restrict__ bq,
    const void* __restrict__ wk, const void* __restrict__ bk,
    const void* __restrict__ wv, const void* __restrict__ bv,
    float* __restrict__ ws)
{
  if (!active(ws, DT)) return;
  const int wid  = threadIdx.x >> 6;
  const int lane = threadIdx.x & 63;
  const int gid  = blockIdx.x * 4 + wid;       // 0..3071
  const int proj = gid >> 10;
  const int j    = gid & 1023;

  const void* W  = (proj == 0) ? wq : (proj == 1) ? wk : wv;
  const void* Bb = (proj == 0) ? bq : (proj == 1) ? bk : bv;
  float* dst = ws + ((proj == 0) ? WS_QH : (proj == 1) ? WS_KH : WS_VH);

  float acc[BSZ];
#pragma unroll
  for (int b = 0; b < BSZ; b++) acc[b] = 0.f;

#pragma unroll
  for (int i = 0; i < 4; i++) {
    float wf[4];
    load4<DT>(W, (long)j * 256 + lane + 64 * i, wf);
#pragma unroll
    for (int b = 0; b < BSZ; b++) {
      float xf[4];
      load4<DT>(x, (long)b * 256 + lane + 64 * i, xf);
      acc[b] += wf[0] * xf[0] + wf[1] * xf[1] + wf[2] * xf[2] + wf[3] * xf[3];
    }
  }
#pragma unroll
  for (int b = 0; b < BSZ; b++)
#pragma unroll
    for (int off = 32; off >= 1; off >>= 1)
      acc[b] += __shfl_xor(acc[b], off);

  if (lane == 0) {
    float bias = ld1<DT>(Bb, j);
#pragma unroll
    for (int b = 0; b < BSZ; b++) dst[b * DM + j] = acc[b] + bias;
  }
}

// ---------------------------------------------------------------------------
// Kernel A2: RoPE q-heads and new-k, both at position 4096. (f32 ws only —
// dtype-independent.) grid = 64 x 256
// ---------------------------------------------------------------------------
__global__ __launch_bounds__(256) void rope_qk(float* __restrict__ ws)
{
  const int tid    = blockIdx.x * 256 + threadIdx.x;   // 0..16383
  const int tensor = tid >> 13;                        // 0=q, 1=k_new
  const int r      = tid & 8191;                       // bh*64 + d
  const int d      = r & 63;

  const float* src = ws + (tensor ? WS_KH : WS_QH);
  float*       dst = ws + (tensor ? WS_KROT : WS_QROT);

  float v = src[r];
  if (d < 32) {
    int j = d >> 1;
    double invf = exp2(-(double)j * (LOG2_THETA / 16.0));
    double ang  = fmod(4096.0 * invf, TWO_PI);
    float c = cosf((float)ang), s = sinf((float)ang);
    float pv = src[r ^ 1];
    v = (d & 1) ? (v * c + pv * s) : (v * c - pv * s);
  }
  dst[r] = v;
}

// ---------------------------------------------------------------------------
// Kernel B: attention over the 4096-cache, flash-decoding split.
// grid = 1024 x 256 (4 waves). lane = 8*pidx + g; g = 8-dim slice, pidx =
// position-in-octet -> 16B(bf16)/32B(f32) loads, fully coalesced per wave.
// Online softmax in log2 domain per octet stream; merged via shfl then LDS.
// RoPE cos/sin via fp32 rotor recurrence (double-reduced init).
// ---------------------------------------------------------------------------
template<int DT>
__global__ __launch_bounds__(256) void attn_chunks(
    const void* __restrict__ kcache,
    const void* __restrict__ vcache,
    float* __restrict__ ws)
{
  if (!active(ws, DT)) return;
  const int wid  = threadIdx.x >> 6;
  const int lane = threadIdx.x & 63;
  const int bh   = blockIdx.x / SPLIT;
  const int chnk = blockIdx.x % SPLIT;
  const int g    = lane & 7;
  const int pidx = lane >> 3;
  const int t0   = chnk * CHUNK + wid * (CHUNK / 4) + pidx;  // wave covers 128 pos
  const int NIT  = CHUNK / 4 / 8;                            // 16 iterations

  __shared__ float sm[4], sl[4], so[4][64];

  // q fragment (loop-invariant, 8 floats)
  float qv[8];
  {
    const float* qr = ws + WS_QROT + bh * HD + g * 8;
#pragma unroll
    for (int i = 0; i < 8; i++) qv[i] = qr[i];
  }

  // RoPE rotors for this lane's 4 freq pairs (only used when g<4)
  float cc[4], ss[4], c8[4], s8[4];
  {
    const int jb = 4 * (g & 3);
#pragma unroll
    for (int m = 0; m < 4; m++) {
      double invf = exp2(-(double)(jb + m) * (LOG2_THETA / 16.0));
      double a0 = fmod((double)t0 * invf, TWO_PI);
      cc[m] = cosf((float)a0); ss[m] = sinf((float)a0);
      double a8 = fmod(8.0 * invf, TWO_PI);
      c8[m] = cosf((float)a8); s8[m] = sinf((float)a8);
    }
  }

  float m2 = -INFINITY, ll = 0.f;
  float o[8];
#pragma unroll
  for (int i = 0; i < 8; i++) o[i] = 0.f;

  float kcur[8], vcur[8];
  load8<DT>(kcache, ((long)bh * CL + t0) * 8 + g, kcur);
  load8<DT>(vcache, ((long)bh * CL + t0) * 8 + g, vcur);

#pragma unroll
  for (int it = 0; it < 16; it++) {
    const int t = t0 + it * 8;
    float kn[8], vn[8];
#pragma unroll
    for (int i = 0; i < 8; i++) { kn[i] = kcur[i]; vn[i] = vcur[i]; }
    if (it < NIT - 1) {
      load8<DT>(kcache, ((long)bh * CL + t + 8) * 8 + g, kn);
      load8<DT>(vcache, ((long)bh * CL + t + 8) * 8 + g, vn);
    }

    float x[8];
#pragma unroll
    for (int i = 0; i < 8; i++) x[i] = kcur[i];

    if (g < 4) {
#pragma unroll
      for (int m = 0; m < 4; m++) {
        float a = x[2 * m], b = x[2 * m + 1];
        x[2 * m]     = a * cc[m] - b * ss[m];
        x[2 * m + 1] = b * cc[m] + a * ss[m];
        float cn = cc[m] * c8[m] - ss[m] * s8[m];
        float sn = ss[m] * c8[m] + cc[m] * s8[m];
        cc[m] = cn; ss[m] = sn;
      }
    }

    float p = 0.f;
#pragma unroll
    for (int i = 0; i < 8; i++) p += x[i] * qv[i];
    p += __shfl_xor(p, 1);
    p += __shfl_xor(p, 2);
    p += __shfl_xor(p, 4);

    const float s2 = p * SM_SCALE_L2;
    const float mn = fmaxf(m2, s2);
    const float al = exp2f(m2 - mn);   // 0 on first iter (m2 = -inf)
    const float pp = exp2f(s2 - mn);
    ll = ll * al + pp;
#pragma unroll
    for (int i = 0; i < 8; i++) o[i] = o[i] * al + pp * vcur[i];
    m2 = mn;

#pragma unroll
    for (int i = 0; i < 8; i++) { kcur[i] = kn[i]; vcur[i] = vn[i]; }
  }

  // merge the 8 position-streams within the wave (xor 8, 16, 32)
#pragma unroll
  for (int off = 8; off < 64; off <<= 1) {
    float om  = __shfl_xor(m2, off);
    float olp = __shfl_xor(ll, off);
    float mn  = fmaxf(m2, om);
    float a   = exp2f(m2 - mn);
    float bsc = exp2f(om - mn);
    ll = ll * a + olp * bsc;
#pragma unroll
    for (int i = 0; i < 8; i++) {
      float oo = __shfl_xor(o[i], off);
      o[i] = o[i] * a + oo * bsc;
    }
    m2 = mn;
  }

  // stage per-wave results in LDS
  if (lane == 0) { sm[wid] = m2; sl[wid] = ll; }
  if (pidx == 0) {
#pragma unroll
    for (int i = 0; i < 8; i++) so[wid][g * 8 + i] = o[i];
  }
  __syncthreads();

  // wave 0 merges the block's 4 wave-partials and writes ONE global partial
  if (wid == 0) {
    float M = fmaxf(fmaxf(sm[0], sm[1]), fmaxf(sm[2], sm[3]));
    float L = 0.f, O = 0.f;
#pragma unroll
    for (int w = 0; w < 4; w++) {
      float sc = exp2f(sm[w] - M);
      L += sc * sl[w];
      O += sc * so[w][lane];
    }
    float* pb = ws + WS_PART + ((size_t)bh * SPLIT + chnk) * PSTRIDE;
    if (lane == 0) { pb[0] = M; pb[1] = L; }
    pb[4 + lane] = O;
  }
}

// ---------------------------------------------------------------------------
// Kernel C: combine 8 partials per (b,h) + the new token at position 4096.
// (f32 ws only — dtype-independent.) grid = 32 x 256
// ---------------------------------------------------------------------------
__global__ __launch_bounds__(256) void combine(float* __restrict__ ws)
{
  const int wid  = threadIdx.x >> 6;
  const int lane = threadIdx.x & 63;
  const int bh   = blockIdx.x * 4 + wid;   // 0..127

  // new-token score: q_rot . k_new_rot
  float p = ws[WS_QROT + bh * HD + lane] * ws[WS_KROT + bh * HD + lane];
#pragma unroll
  for (int off = 1; off < 64; off <<= 1) p += __shfl_xor(p, off);
  const float s2 = p * SM_SCALE_L2;

  float M = -INFINITY, L = 0.f, O = 0.f;
  const float* pb = ws + WS_PART + (size_t)bh * SPLIT * PSTRIDE;
#pragma unroll
  for (int pi = 0; pi < SPLIT; pi++) {
    const float* pp = pb + pi * PSTRIDE;
    float mp = pp[0], lp = pp[1], op = pp[4 + lane];
    float mn = fmaxf(M, mp);
    float a  = exp2f(M - mn);
    float bb = exp2f(mp - mn);
    O = O * a + op * bb;
    L = L * a + lp * bb;
    M = mn;
  }
  // fold in the new token
  {
    float vn = ws[WS_VH + bh * HD + lane];
    float mn = fmaxf(M, s2);
    float a  = exp2f(M - mn);
    float pn = exp2f(s2 - mn);
    O = O * a + pn * vn;
    L = L * a + pn;
  }
  ws[WS_HEAD + bh * HD + lane] = O / L;
}

// ---------------------------------------------------------------------------
// Kernel D: output projection GEMV. Wave per out-col j, all 8 batches.
// grid = 256 x 256
// ---------------------------------------------------------------------------
template<int DT>
__global__ __launch_bounds__(256) void out_gemv(
    const float* __restrict__ ws,
    const void* __restrict__ wo,
    const void* __restrict__ bo,
    void* __restrict__ out)
{
  if (!active(ws, DT)) return;
  const int wid  = threadIdx.x >> 6;
  const int lane = threadIdx.x & 63;
  const int j    = blockIdx.x * 4 + wid;       // 0..1023

  const float4* Xr = reinterpret_cast<const float4*>(ws + WS_HEAD);

  float acc[BSZ];
#pragma unroll
  for (int b = 0; b < BSZ; b++) acc[b] = 0.f;

#pragma unroll
  for (int i = 0; i < 4; i++) {
    float wf[4];
    load4<DT>(wo, (long)j * 256 + lane + 64 * i, wf);
#pragma unroll
    for (int b = 0; b < BSZ; b++) {
      float4 xf = Xr[b * 256 + lane + 64 * i];
      acc[b] += wf[0] * xf.x + wf[1] * xf.y + wf[2] * xf.z + wf[3] * xf.w;
    }
  }
#pragma unroll
  for (int b = 0; b < BSZ; b++)
#pragma unroll
    for (int off = 32; off >= 1; off >>= 1)
      acc[b] += __shfl_xor(acc[b], off);

  if (lane == 0) {
    float bias = ld1<DT>(bo, j);
#pragma unroll
    for (int b = 0; b < BSZ; b++)
      st1<DT>(out, b * DM + j, acc[b] + bias);
  }
}

// ---------------------------------------------------------------------------
extern "C" void kernel_launch(void* const* d_in, const int* in_sizes, int n_in,
                              void* d_out, int out_size, void* d_ws, size_t ws_size,
                              hipStream_t stream)
{
  const void* q  = d_in[0];
  const void* kc = d_in[1];
  const void* vc = d_in[2];
  const void* wq = d_in[3];
  const void* bq = d_in[4];
  const void* wk = d_in[5];
  const void* bk = d_in[6];
  const void* wv = d_in[7];
  const void* bv = d_in[8];
  const void* wo = d_in[9];
  const void* bo = d_in[10];
  float* ws = (float*)d_ws;

  detect_dtype<<<1, 256, 0, stream>>>((const unsigned*)q, ws);

  qkv_gemv<0><<<768, 256, 0, stream>>>(q, wq, bq, wk, bk, wv, bv, ws);
  qkv_gemv<1><<<768, 256, 0, stream>>>(q, wq, bq, wk, bk, wv, bv, ws);

  rope_qk<<<64, 256, 0, stream>>>(ws);

  attn_chunks<0><<<128 * SPLIT, 256, 0, stream>>>(kc, vc, ws);
  attn_chunks<1><<<128 * SPLIT, 256, 0, stream>>>(kc, vc, ws);

  combine<<<32, 256, 0, stream>>>(ws);

  out_gemv<0><<<256, 256, 0, stream>>>(ws, wo, bo, d_out);
  out_gemv<1><<<256, 256, 0, stream>>>(ws, wo, bo, d_out);
}

// Round 4
// 322.764 us; speedup vs baseline: 1.0294x; 1.0294x over previous
//
#include <hip/hip_runtime.h>
#include <hip/hip_bf16.h>
#include <math.h>

// Problem constants
#define NH    16
#define HD    64
#define DM    1024
#define BSZ   8
#define CL    4096
#define SPLIT 8                 // cache chunks per (b,h); one block per chunk
#define CHUNK (CL / SPLIT)      // 512 positions per block (4 waves x 128)
#define PSTRIDE 68              // floats per partial: [0]=m [1]=l [2..3]=pad [4..67]=o

// Workspace layout (float-word offsets) — identical to round-3-proven layout
#define WS_QH   0                                   // raw q heads   (8192)
#define WS_KH   8192                                // raw new-k     (8192)
#define WS_VH   16384                               // new-v         (8192)
#define WS_PART 40960                               // 128*8*68 = 69632 floats
#define WS_HEAD (40960 + 128 * SPLIT * PSTRIDE)     // head outputs  (8192)

#define LOG2_THETA 13.287712379549449               // log2(10000)
#define TWO_PI     6.283185307179586476925286766559
#define SM_SCALE_L2 (0.125f * 1.4426950408889634f)  // 1/sqrt(64) * log2(e)

__device__ __forceinline__ void bf2x(unsigned u, float& a, float& b) {
  union { unsigned i; float f; } lo, hi;
  lo.i = u << 16;
  hi.i = u & 0xffff0000u;
  a = lo.f; b = hi.f;
}

// ---- dtype-generic element access (DT=0: bf16, DT=1: f32) -----------------
template<int DT> __device__ __forceinline__ void load4(const void* p, long i4, float* o);
template<> __device__ __forceinline__ void load4<0>(const void* p, long i4, float* o) {
  uint2 w = ((const uint2*)p)[i4];
  bf2x(w.x, o[0], o[1]); bf2x(w.y, o[2], o[3]);
}
template<> __device__ __forceinline__ void load4<1>(const void* p, long i4, float* o) {
  float4 f = ((const float4*)p)[i4];
  o[0] = f.x; o[1] = f.y; o[2] = f.z; o[3] = f.w;
}

template<int DT> __device__ __forceinline__ void load8(const void* p, long i8, float* o);
template<> __device__ __forceinline__ void load8<0>(const void* p, long i8, float* o) {
  uint4 u = ((const uint4*)p)[i8];
  bf2x(u.x, o[0], o[1]); bf2x(u.y, o[2], o[3]);
  bf2x(u.z, o[4], o[5]); bf2x(u.w, o[6], o[7]);
}
template<> __device__ __forceinline__ void load8<1>(const void* p, long i8, float* o) {
  const float4* f = (const float4*)p + 2 * i8;
  float4 a = f[0], b = f[1];
  o[0] = a.x; o[1] = a.y; o[2] = a.z; o[3] = a.w;
  o[4] = b.x; o[5] = b.y; o[6] = b.z; o[7] = b.w;
}

template<int DT> __device__ __forceinline__ float ld1(const void* p, int i);
template<> __device__ __forceinline__ float ld1<0>(const void* p, int i) {
  return __bfloat162float(((const __hip_bfloat16*)p)[i]);
}
template<> __device__ __forceinline__ float ld1<1>(const void* p, int i) {
  return ((const float*)p)[i];
}

template<int DT> __device__ __forceinline__ void st1(void* p, int i, float v);
template<> __device__ __forceinline__ void st1<0>(void* p, int i, float v) {
  ((__hip_bfloat16*)p)[i] = __float2bfloat16(v);
}
template<> __device__ __forceinline__ void st1<1>(void* p, int i, float v) {
  ((float*)p)[i] = v;
}

// Per-block dtype self-detection: every wave reads q words 0..63 (same words
// for all waves -> deterministic block-uniform decision). f32 data viewed as
// bf16 pairs has random exponent bits in the low half: P(miss) ~ 0.62^64.
__device__ __forceinline__ bool data_is_f32(const unsigned* qw) {
  float a, b;
  bf2x(qw[threadIdx.x & 63], a, b);
  return __any(!(fabsf(a) < 1e10f) || !(fabsf(b) < 1e10f)) != 0;
}

// ---------------------------------------------------------------------------
// Kernel A: fused QKV GEMV. One wave per (proj, out-col j); computes all 8
// batches so each weight row is read exactly once. grid = 768 x 256
// ---------------------------------------------------------------------------
template<int DT>
__global__ __launch_bounds__(256) void qkv_gemv(
    const void* __restrict__ x,
    const void* __restrict__ wq, const void* __restrict__ bq,
    const void* __restrict__ wk, const void* __restrict__ bk,
    const void* __restrict__ wv, const void* __restrict__ bv,
    float* __restrict__ ws)
{
  if (data_is_f32((const unsigned*)x) != (DT == 1)) return;
  const int wid  = threadIdx.x >> 6;
  const int lane = threadIdx.x & 63;
  const int gid  = blockIdx.x * 4 + wid;       // 0..3071
  const int proj = gid >> 10;
  const int j    = gid & 1023;

  const void* W  = (proj == 0) ? wq : (proj == 1) ? wk : wv;
  const void* Bb = (proj == 0) ? bq : (proj == 1) ? bk : bv;
  float* dst = ws + ((proj == 0) ? WS_QH : (proj == 1) ? WS_KH : WS_VH);

  float acc[BSZ];
#pragma unroll
  for (int b = 0; b < BSZ; b++) acc[b] = 0.f;

#pragma unroll
  for (int i = 0; i < 4; i++) {
    float wf[4];
    load4<DT>(W, (long)j * 256 + lane + 64 * i, wf);
#pragma unroll
    for (int b = 0; b < BSZ; b++) {
      float xf[4];
      load4<DT>(x, (long)b * 256 + lane + 64 * i, xf);
      acc[b] += wf[0] * xf[0] + wf[1] * xf[1] + wf[2] * xf[2] + wf[3] * xf[3];
    }
  }
#pragma unroll
  for (int b = 0; b < BSZ; b++)
#pragma unroll
    for (int off = 32; off >= 1; off >>= 1)
      acc[b] += __shfl_xor(acc[b], off);

  if (lane == 0) {
    float bias = ld1<DT>(Bb, j);
#pragma unroll
    for (int b = 0; b < BSZ; b++) dst[b * DM + j] = acc[b] + bias;
  }
}

// ---------------------------------------------------------------------------
// Kernel B: attention over the 4096-cache, flash-decoding split, two-phase.
// grid = 1024 x 256 (4 waves). lane = 8*pidx + g; g = 8-dim slice, pidx =
// position-in-octet. Wave covers 128 positions = 16 octets.
// Phase A: stream K (4-deep ring prefetch), compute all 16 scores — no
// cross-iteration dependency (RoPE rotor recurrence only, 2-FMA chain).
// Between: one local max + 16 exp2.
// Phase B: stream V (4-deep ring), pure FMA accumulation.
// Merge: shfl over pidx groups, LDS over 4 waves -> 1 partial per block.
// q is roped in-kernel (position 4096, double-reduced angles).
// ---------------------------------------------------------------------------
template<int DT>
__global__ __launch_bounds__(256) void attn_chunks(
    const unsigned* __restrict__ qdet,
    const void* __restrict__ kcache,
    const void* __restrict__ vcache,
    float* __restrict__ ws)
{
  if (data_is_f32(qdet) != (DT == 1)) return;
  const int wid  = threadIdx.x >> 6;
  const int lane = threadIdx.x & 63;
  const int bh   = blockIdx.x / SPLIT;
  const int chnk = blockIdx.x % SPLIT;
  const int g    = lane & 7;
  const int pidx = lane >> 3;
  const int t0   = chnk * CHUNK + wid * 128 + pidx;   // wave covers 128 pos

  __shared__ float smx[4], sl[4], so[4][64];

  // q fragment, roped at position 4096 (dims g*8 .. g*8+7; freq j = 4g+m)
  float qv[8];
  {
    const float* qr = ws + WS_QH + bh * HD + g * 8;
#pragma unroll
    for (int i = 0; i < 8; i++) qv[i] = qr[i];
    if (g < 4) {
#pragma unroll
      for (int m = 0; m < 4; m++) {
        double invf = exp2(-(double)(4 * g + m) * (LOG2_THETA / 16.0));
        double ang  = fmod(4096.0 * invf, TWO_PI);
        float c = cosf((float)ang), s = sinf((float)ang);
        float e = qv[2 * m], o = qv[2 * m + 1];
        qv[2 * m]     = e * c - o * s;
        qv[2 * m + 1] = o * c + e * s;
      }
    }
  }

  // RoPE rotors for this lane's 4 freq pairs (used when g<4), step 8
  float cc[4], ss[4], c8[4], s8[4];
  {
    const int jb = 4 * (g & 3);
#pragma unroll
    for (int m = 0; m < 4; m++) {
      double invf = exp2(-(double)(jb + m) * (LOG2_THETA / 16.0));
      double a0 = fmod((double)t0 * invf, TWO_PI);
      cc[m] = cosf((float)a0); ss[m] = sinf((float)a0);
      double a8 = fmod(8.0 * invf, TWO_PI);
      c8[m] = cosf((float)a8); s8[m] = sinf((float)a8);
    }
  }

  const long rbase = (long)bh * CL + t0;

  // ---- Phase A: K stream -> 16 scores --------------------------------------
  float kr[4][8];
#pragma unroll
  for (int i = 0; i < 4; i++) load8<DT>(kcache, (rbase + 8 * i) * 8 + g, kr[i]);

  float s[16];
#pragma unroll
  for (int o = 0; o < 16; o++) {
    float x[8];
#pragma unroll
    for (int i = 0; i < 8; i++) x[i] = kr[o & 3][i];
    if (o + 4 < 16) load8<DT>(kcache, (rbase + 8 * (o + 4)) * 8 + g, kr[o & 3]);

    if (g < 4) {
#pragma unroll
      for (int m = 0; m < 4; m++) {
        float a = x[2 * m], b = x[2 * m + 1];
        x[2 * m]     = a * cc[m] - b * ss[m];
        x[2 * m + 1] = b * cc[m] + a * ss[m];
        float cn = cc[m] * c8[m] - ss[m] * s8[m];
        float sn = ss[m] * c8[m] + cc[m] * s8[m];
        cc[m] = cn; ss[m] = sn;
      }
    }

    float p = 0.f;
#pragma unroll
    for (int i = 0; i < 8; i++) p += x[i] * qv[i];
    p += __shfl_xor(p, 1);
    p += __shfl_xor(p, 2);
    p += __shfl_xor(p, 4);
    s[o] = p * SM_SCALE_L2;
  }

  // ---- local softmax over this lane's 16 positions -------------------------
  float m2 = s[0];
#pragma unroll
  for (int o = 1; o < 16; o++) m2 = fmaxf(m2, s[o]);
  float ll = 0.f;
#pragma unroll
  for (int o = 0; o < 16; o++) { s[o] = exp2f(s[o] - m2); ll += s[o]; }

  // ---- Phase B: V stream -> weighted accumulation --------------------------
  float vr[4][8];
#pragma unroll
  for (int i = 0; i < 4; i++) load8<DT>(vcache, (rbase + 8 * i) * 8 + g, vr[i]);

  float oa[8];
#pragma unroll
  for (int i = 0; i < 8; i++) oa[i] = 0.f;
#pragma unroll
  for (int o = 0; o < 16; o++) {
    float v[8];
#pragma unroll
    for (int i = 0; i < 8; i++) v[i] = vr[o & 3][i];
    if (o + 4 < 16) load8<DT>(vcache, (rbase + 8 * (o + 4)) * 8 + g, vr[o & 3]);
#pragma unroll
    for (int i = 0; i < 8; i++) oa[i] = fmaf(s[o], v[i], oa[i]);
  }

  // ---- merge the 8 position-streams within the wave (xor 8, 16, 32) --------
#pragma unroll
  for (int off = 8; off < 64; off <<= 1) {
    float om  = __shfl_xor(m2, off);
    float olp = __shfl_xor(ll, off);
    float mn  = fmaxf(m2, om);
    float a   = exp2f(m2 - mn);
    float bsc = exp2f(om - mn);
    ll = ll * a + olp * bsc;
#pragma unroll
    for (int i = 0; i < 8; i++) {
      float oo = __shfl_xor(oa[i], off);
      oa[i] = oa[i] * a + oo * bsc;
    }
    m2 = mn;
  }

  // ---- stage per-wave results in LDS, wave 0 merges ------------------------
  if (lane == 0) { smx[wid] = m2; sl[wid] = ll; }
  if (pidx == 0) {
#pragma unroll
    for (int i = 0; i < 8; i++) so[wid][g * 8 + i] = oa[i];
  }
  __syncthreads();

  if (wid == 0) {
    float M = fmaxf(fmaxf(smx[0], smx[1]), fmaxf(smx[2], smx[3]));
    float L = 0.f, O = 0.f;
#pragma unroll
    for (int w = 0; w < 4; w++) {
      float sc = exp2f(smx[w] - M);
      L += sc * sl[w];
      O += sc * so[w][lane];
    }
    float* pb = ws + WS_PART + ((size_t)bh * SPLIT + chnk) * PSTRIDE;
    if (lane == 0) { pb[0] = M; pb[1] = L; }
    pb[4 + lane] = O;
  }
}

// ---------------------------------------------------------------------------
// Kernel C: combine 8 partials per (b,h) + the new token at position 4096.
// Ropes q and k_new in-kernel (same angle for both). grid = 32 x 256
// ---------------------------------------------------------------------------
__global__ __launch_bounds__(256) void combine(float* __restrict__ ws)
{
  const int wid  = threadIdx.x >> 6;
  const int lane = threadIdx.x & 63;
  const int bh   = blockIdx.x * 4 + wid;   // 0..127

  float qd = ws[WS_QH + bh * HD + lane];
  float kd = ws[WS_KH + bh * HD + lane];
  float qp = ws[WS_QH + bh * HD + (lane ^ 1)];
  float kp = ws[WS_KH + bh * HD + (lane ^ 1)];
  float qrot = qd, krot = kd;
  if (lane < 32) {
    int j = lane >> 1;
    double invf = exp2(-(double)j * (LOG2_THETA / 16.0));
    double ang  = fmod(4096.0 * invf, TWO_PI);
    float c = cosf((float)ang), s = sinf((float)ang);
    if (lane & 1) { qrot = qd * c + qp * s; krot = kd * c + kp * s; }
    else          { qrot = qd * c - qp * s; krot = kd * c - kp * s; }
  }

  float p = qrot * krot;
#pragma unroll
  for (int off = 1; off < 64; off <<= 1) p += __shfl_xor(p, off);
  const float s2 = p * SM_SCALE_L2;

  float M = -INFINITY, L = 0.f, O = 0.f;
  const float* pb = ws + WS_PART + (size_t)bh * SPLIT * PSTRIDE;
#pragma unroll
  for (int pi = 0; pi < SPLIT; pi++) {
    const float* pp = pb + pi * PSTRIDE;
    float mp = pp[0], lp = pp[1], op = pp[4 + lane];
    float mn = fmaxf(M, mp);
    float a  = exp2f(M - mn);
    float bb = exp2f(mp - mn);
    O = O * a + op * bb;
    L = L * a + lp * bb;
    M = mn;
  }
  {
    float vn = ws[WS_VH + bh * HD + lane];
    float mn = fmaxf(M, s2);
    float a  = exp2f(M - mn);
    float pn = exp2f(s2 - mn);
    O = O * a + pn * vn;
    L = L * a + pn;
  }
  ws[WS_HEAD + bh * HD + lane] = O / L;
}

// ---------------------------------------------------------------------------
// Kernel D: output projection GEMV. Wave per out-col j, all 8 batches.
// grid = 256 x 256
// ---------------------------------------------------------------------------
template<int DT>
__global__ __launch_bounds__(256) void out_gemv(
    const unsigned* __restrict__ qdet,
    const float* __restrict__ ws,
    const void* __restrict__ wo,
    const void* __restrict__ bo,
    void* __restrict__ out)
{
  if (data_is_f32(qdet) != (DT == 1)) return;
  const int wid  = threadIdx.x >> 6;
  const int lane = threadIdx.x & 63;
  const int j    = blockIdx.x * 4 + wid;       // 0..1023

  const float4* Xr = reinterpret_cast<const float4*>(ws + WS_HEAD);

  float acc[BSZ];
#pragma unroll
  for (int b = 0; b < BSZ; b++) acc[b] = 0.f;

#pragma unroll
  for (int i = 0; i < 4; i++) {
    float wf[4];
    load4<DT>(wo, (long)j * 256 + lane + 64 * i, wf);
#pragma unroll
    for (int b = 0; b < BSZ; b++) {
      float4 xf = Xr[b * 256 + lane + 64 * i];
      acc[b] += wf[0] * xf.x + wf[1] * xf.y + wf[2] * xf.z + wf[3] * xf.w;
    }
  }
#pragma unroll
  for (int b = 0; b < BSZ; b++)
#pragma unroll
    for (int off = 32; off >= 1; off >>= 1)
      acc[b] += __shfl_xor(acc[b], off);

  if (lane == 0) {
    float bias = ld1<DT>(bo, j);
#pragma unroll
    for (int b = 0; b < BSZ; b++)
      st1<DT>(out, b * DM + j, acc[b] + bias);
  }
}

// ---------------------------------------------------------------------------
extern "C" void kernel_launch(void* const* d_in, const int* in_sizes, int n_in,
                              void* d_out, int out_size, void* d_ws, size_t ws_size,
                              hipStream_t stream)
{
  const void* q  = d_in[0];
  const void* kc = d_in[1];
  const void* vc = d_in[2];
  const void* wq = d_in[3];
  const void* bq = d_in[4];
  const void* wk = d_in[5];
  const void* bk = d_in[6];
  const void* wv = d_in[7];
  const void* bv = d_in[8];
  const void* wo = d_in[9];
  const void* bo = d_in[10];
  float* ws = (float*)d_ws;
  const unsigned* qdet = (const unsigned*)q;

  qkv_gemv<0><<<768, 256, 0, stream>>>(q, wq, bq, wk, bk, wv, bv, ws);
  qkv_gemv<1><<<768, 256, 0, stream>>>(q, wq, bq, wk, bk, wv, bv, ws);

  attn_chunks<0><<<128 * SPLIT, 256, 0, stream>>>(qdet, kc, vc, ws);
  attn_chunks<1><<<128 * SPLIT, 256, 0, stream>>>(qdet, kc, vc, ws);

  combine<<<32, 256, 0, stream>>>(ws);

  out_gemv<0><<<256, 256, 0, stream>>>(qdet, ws, wo, bo, d_out);
  out_gemv<1><<<256, 256, 0, stream>>>(qdet, ws, wo, bo, d_out);
}